// Round 4
// baseline (233.060 us; speedup 1.0000x reference)
//
#include <hip/hip_runtime.h>
#include <hip/hip_cooperative_groups.h>
#include <hip/hip_bf16.h>
#include <math.h>

// MultiHeadAttentionQuantum, B=2048 S=1 E=1024 H=128 DK=NW=8
// All inputs/outputs float32.
//
// Algebra: S==1 -> attention out == v = x @ Wv^T (wq,wk dead).
// RX compose additively; CNOTs are XOR basis permutations ->
//   t_j = cos(v_j + rx_j);  qout[0]=t1*...*t7;  qout[w>=1]=t0*...*tw
// out = qout @ Wc^T + bc
//
// R9 (split-K), R10 (counted-vmcnt pipeline): null -> K-loop throughput is
// not binding. R11 (f32 reg-staged fusion): -9us regression -> keep bf16 +
// global_load_lds staging, convert once at HBM rate.
// R12: test the LAST hypothesis -- dispatch transitions. One cooperative
// kernel (512 blocks x 512 thr = exactly 2/CU co-resident), phases =
// bit-identical R0-proven code: [cvt x/wv/wc] gridsync [GEMM1+quantum->V]
// gridsync [GEMM2+bias->out]. Removes 2 launch gaps + 2 ramp/tail pairs.

#define BB 2048
#define EN 1024

typedef short s16x8 __attribute__((ext_vector_type(8)));
typedef float f32x4 __attribute__((ext_vector_type(4)));

union Frag { s16x8 v; __hip_bfloat16 h[8]; };

__device__ inline s16x8 cvt_frag(f32x4 lo, f32x4 hi) {
    Frag u;
    #pragma unroll
    for (int j = 0; j < 4; ++j) {
        u.h[j]     = __float2bfloat16(lo[j]);
        u.h[4 + j] = __float2bfloat16(hi[j]);
    }
    return u.v;
}

// async 16B/lane global -> LDS (lds base wave-uniform; HW adds lane*16)
__device__ inline void gll16(const __hip_bfloat16* g, __hip_bfloat16* l) {
    __builtin_amdgcn_global_load_lds(
        (const __attribute__((address_space(1))) void*)g,
        (__attribute__((address_space(3))) void*)l,
        16, 0, 0);
}

// R0-proven 64x64 GEMM tile: C[m,n] = sum_k A[m,k]*W[n,k], bf16 operands.
// 8 waves (4m x 2n), wave tile 16x32, BK=64, double-buffered frag-ordered
// LDS (32 KB): frag-tile = 512 elems (16 rows x 32 k), lane l's fragment at
// tile_base + l*8. A tile (mt,kt) at (mt*2+kt)*512; B (nt,kt) at
// 4096+(nt*2+kt)*512. Staging via global_load_lds, 2 frag-tiles per wave.
__device__ __forceinline__ void gemm64(
        const __hip_bfloat16* __restrict__ A,
        const __hip_bfloat16* __restrict__ W,
        __hip_bfloat16* lds, int m0, int n0, int tid, f32x4* acc)
{
    const int wave = tid >> 6, lane = tid & 63;
    const int l15 = lane & 15, lq = lane >> 4;
    const int wmt = wave >> 1;          // 0..3  (16-row wave tile)
    const int wnt = wave & 1;           // 0..1  (32-col wave tile)

    const __hip_bfloat16* gsrc[2];
    int ldst[2];
    #pragma unroll
    for (int i = 0; i < 2; ++i) {
        const int t = wave * 2 + i;
        int row, lofs;
        const __hip_bfloat16* base;
        if (t < 8) { const int mt = t >> 1; row = m0 + mt * 16 + l15; base = A; lofs = t * 512; }
        else       { const int u = t - 8;   row = n0 + (u >> 1) * 16 + l15; base = W; lofs = 4096 + u * 512; }
        gsrc[i] = base + (size_t)row * EN + (t & 1) * 32 + lq * 8;
        ldst[i] = lofs;
    }

    #pragma unroll
    for (int i = 0; i < 2; ++i) gll16(gsrc[i], &lds[ldst[i]]);
    __syncthreads();

    int p = 0;
    for (int k0 = 64; k0 <= EN; k0 += 64) {
        if (k0 < EN) {
            const int q = p ^ 1;
            #pragma unroll
            for (int i = 0; i < 2; ++i) gll16(gsrc[i] + k0, &lds[q * 8192 + ldst[i]]);
        }
        const __hip_bfloat16* Ab = &lds[p * 8192];
        const __hip_bfloat16* Bb = Ab + 4096;
        #pragma unroll
        for (int kt = 0; kt < 2; ++kt) {
            s16x8 a = *(const s16x8*)&Ab[(wmt * 2 + kt) * 512 + lane * 8];
            #pragma unroll
            for (int j = 0; j < 2; ++j) {
                s16x8 b = *(const s16x8*)&Bb[((wnt * 2 + j) * 2 + kt) * 512 + lane * 8];
                acc[j] = __builtin_amdgcn_mfma_f32_16x16x32_bf16(a, b, acc[j], 0, 0, 0);
            }
        }
        __syncthreads();
        p ^= 1;
    }
}

__global__ __launch_bounds__(512, 4) void mega_kernel(
        const float* __restrict__ x,  const float* __restrict__ wv,
        const float* __restrict__ wc, const float* __restrict__ bc,
        const float* __restrict__ rx,
        __hip_bfloat16* __restrict__ xb, __hip_bfloat16* __restrict__ wvb,
        __hip_bfloat16* __restrict__ wcb,
        __hip_bfloat16* __restrict__ V, float* __restrict__ out)
{
    __shared__ __align__(16) unsigned char smem[33792];
    __hip_bfloat16* lds = (__hip_bfloat16*)smem;

    const int tid = threadIdx.x;
    const int bid = blockIdx.x;

    // ---- phase 0: cvt x (262144 groups) + wv/wc (131072 each) to bf16.
    // 262144 threads, 2 groups of 8 f32 each, coalesced f32x4 pairs.
    {
        const int NG = (EN * EN) / 8;               // 131072
        const int gt = bid * 512 + tid;             // 0..262143
        {
            f32x4 lo = *(const f32x4*)(x + (size_t)gt * 8);
            f32x4 hi = *(const f32x4*)(x + (size_t)gt * 8 + 4);
            *(s16x8*)(xb + (size_t)gt * 8) = cvt_frag(lo, hi);
        }
        {
            const float* s; __hip_bfloat16* d; size_t off;
            if (gt < NG) { s = wv; d = wvb; off = (size_t)gt * 8; }
            else         { s = wc; d = wcb; off = (size_t)(gt - NG) * 8; }
            f32x4 lo = *(const f32x4*)(s + off);
            f32x4 hi = *(const f32x4*)(s + off + 4);
            *(s16x8*)(d + off) = cvt_frag(lo, hi);
        }
    }
    cooperative_groups::this_grid().sync();

    const int bx = bid & 31, by = bid >> 5;         // 32 m-tiles x 16 n-tiles
    const int m0 = bx * 64, n0 = by * 64;
    const int wave = tid >> 6, lane = tid & 63;
    const int l15 = lane & 15, lq = lane >> 4;
    const int wmt = wave >> 1, wnt = wave & 1;

    // ---- phase 1: GEMM1 (xb @ wvb^T) + quantum epilogue -> bf16 V
    {
        f32x4 acc[2] = {};
        gemm64(xb, wvb, lds, m0, n0, tid, acc);

        // quantum epilogue: acc -> LDS f32 64x68 -> cos/products -> bf16 V
        float* sb = (float*)smem;       // 17408 B; bufs dead past final barrier
        #pragma unroll
        for (int j = 0; j < 2; ++j) {
            const int col = wnt * 32 + j * 16 + l15;
            #pragma unroll
            for (int r = 0; r < 4; ++r)
                sb[(wmt * 16 + lq * 4 + r) * 68 + col] = acc[j][r];
        }
        __syncthreads();
        const int row = tid >> 3, g = tid & 7;      // 64 rows x 8 groups
        const float* pv = &sb[row * 68 + g * 8];
        float t[8];
        #pragma unroll
        for (int j = 0; j < 8; ++j) t[j] = __cosf(pv[j] + rx[j]);
        Frag o;
        float suf = t[1];
        #pragma unroll
        for (int j = 2; j < 8; ++j) suf *= t[j];
        o.h[0] = __float2bfloat16(suf);
        float pr = t[0];
        #pragma unroll
        for (int j = 1; j < 8; ++j) { pr *= t[j]; o.h[j] = __float2bfloat16(pr); }
        *(s16x8*)(V + (size_t)(m0 + row) * EN + n0 + g * 8) = o.v;
    }
    cooperative_groups::this_grid().sync();

    // ---- phase 2: GEMM2 (V @ wcb^T) + bias -> f32 out
    {
        f32x4 acc[2] = {};
        gemm64(V, wcb, lds, m0, n0, tid, acc);

        #pragma unroll
        for (int j = 0; j < 2; ++j) {
            const int col = n0 + wnt * 32 + j * 16 + l15;
            const float bv = bc[col];
            #pragma unroll
            for (int r = 0; r < 4; ++r) {
                const int row = m0 + wmt * 16 + lq * 4 + r;
                out[(size_t)row * EN + col] = acc[j][r] + bv;
            }
        }
    }
}

extern "C" void kernel_launch(void* const* d_in, const int* in_sizes, int n_in,
                              void* d_out, int out_size, void* d_ws, size_t ws_size,
                              hipStream_t stream)
{
    // inputs: x, wq, wk, wv, wc, bc, rx_params (wq/wk dead: S==1)
    const float* x  = (const float*)d_in[0];
    const float* wv = (const float*)d_in[3];
    const float* wc = (const float*)d_in[4];
    const float* bc = (const float*)d_in[5];
    const float* rx = (const float*)d_in[6];
    float* out = (float*)d_out;

    const size_t XE = (size_t)BB * EN;   // 2M elems
    const size_t WE = (size_t)EN * EN;   // 1M elems

    // ws (12 MB): [xb 4MB | wvb 2MB | wcb 2MB | V 4MB]
    __hip_bfloat16* xb  = (__hip_bfloat16*)d_ws;
    __hip_bfloat16* wvb = xb + XE;
    __hip_bfloat16* wcb = wvb + WE;
    __hip_bfloat16* V   = wcb + WE;

    void* args[] = { (void*)&x, (void*)&wv, (void*)&wc, (void*)&bc, (void*)&rx,
                     (void*)&xb, (void*)&wvb, (void*)&wcb, (void*)&V, (void*)&out };
    hipLaunchCooperativeKernel(mega_kernel, dim3(512), dim3(512), args, 0, stream);
}

// Round 5
// 113.397 us; speedup vs baseline: 2.0553x; 2.0553x over previous
//
#include <hip/hip_runtime.h>
#include <hip/hip_bf16.h>
#include <math.h>

// MultiHeadAttentionQuantum, B=2048 S=1 E=1024 H=128 DK=NW=8
// All inputs/outputs float32.
//
// Algebra: S==1 -> attention out == v = x @ Wv^T (wq,wk dead).
// RX compose additively; CNOTs are XOR basis permutations ->
//   t_j = cos(v_j + rx_j);  qout[0]=t1*...*t7;  qout[w>=1]=t0*...*tw
// out = qout @ Wc^T + bc
//
// Ledger: R0 113.0 (3-kernel, 64x64, BK=64) | split-K null | counted-vmcnt
// null | f32 reg-staged fusion -9.8 | coop-gridsync fusion -120 (gridsync
// ~60us each). GEMMs don't respond to throughput levers -> test step-count
// serialization: BK=128 (8 barrier-steps instead of 16, same total MFMA &
// bytes). LDS 64KB/block, still exactly 2 blocks/CU. cvt3 + epilogues are
// bit-identical R0 code.

#define BB 2048
#define EN 1024

typedef short s16x8 __attribute__((ext_vector_type(8)));
typedef float f32x4 __attribute__((ext_vector_type(4)));

union Frag { s16x8 v; __hip_bfloat16 h[8]; };

__device__ inline s16x8 cvt_frag(f32x4 lo, f32x4 hi) {
    Frag u;
    #pragma unroll
    for (int j = 0; j < 4; ++j) {
        u.h[j]     = __float2bfloat16(lo[j]);
        u.h[4 + j] = __float2bfloat16(hi[j]);
    }
    return u.v;
}

// async 16B/lane global -> LDS (lds base wave-uniform; HW adds lane*16)
__device__ inline void gll16(const __hip_bfloat16* g, __hip_bfloat16* l) {
    __builtin_amdgcn_global_load_lds(
        (const __attribute__((address_space(1))) void*)g,
        (__attribute__((address_space(3))) void*)l,
        16, 0, 0);
}

// Convert x (262144 groups), wv, wc (131072 groups each) -> bf16.
__global__ __launch_bounds__(256) void cvt3_kernel(
        const float* __restrict__ x, const float* __restrict__ wv,
        const float* __restrict__ wc,
        __hip_bfloat16* __restrict__ xb, __hip_bfloat16* __restrict__ wvb,
        __hip_bfloat16* __restrict__ wcb)
{
    const int g = blockIdx.x * 256 + threadIdx.x;   // 0 .. 524287
    const int NX = (BB * EN) / 8;                   // 262144
    const int NG = (EN * EN) / 8;                   // 131072
    const float* s; __hip_bfloat16* d; size_t off;
    if (g < NX)           { s = x;  d = xb;  off = (size_t)g * 8; }
    else if (g < NX + NG) { s = wv; d = wvb; off = (size_t)(g - NX) * 8; }
    else                  { s = wc; d = wcb; off = (size_t)(g - NX - NG) * 8; }
    f32x4 lo = *(const f32x4*)(s + off);
    f32x4 hi = *(const f32x4*)(s + off + 4);
    *(s16x8*)(d + off) = cvt_frag(lo, hi);
}

// GEMM: C[m,n] = sum_k A[m,k]*W[n,k]; A 2048xEN bf16, W ENxEN bf16.
// Tile 64x64, 512 thr = 8 waves (4m x 2n), wave tile 16x32, BK=128,
// double-buffered frag-ordered LDS (64 KB): frag-tile = 512 elems (16 rows
// x 32 k), lane l's fragment at tile_base + l*8 elems. Per 32KB buffer:
// A tile (mt,kt) at (mt*4+kt)*512 (mt,kt in 0..3); B tile (nt,kt) at
// 8192+(nt*4+kt)*512. Staging: wave stages 4 frag-tiles t = wave*4+i via
// global_load_lds. 8 K-steps, one __syncthreads per step (R0-proven sync).
// EPI 0: quantum epilogue (in-LDS 64x68 transpose) -> bf16 V.
// EPI 1: +bias -> f32 out.
template <int EPI>
__global__ __launch_bounds__(512, 4) void gemm_kernel(
        const __hip_bfloat16* __restrict__ A,
        const __hip_bfloat16* __restrict__ W,
        const float* __restrict__ bias, const float* __restrict__ rx,
        void* __restrict__ Cv)
{
    __shared__ __align__(16) unsigned char smem[65536];
    __hip_bfloat16* lds = (__hip_bfloat16*)smem;

    const int tid  = threadIdx.x;
    const int wave = tid >> 6, lane = tid & 63;
    const int l15 = lane & 15, lq = lane >> 4;
    const int m0 = blockIdx.x * 64, n0 = blockIdx.y * 64;
    const int wmt = wave >> 1;          // 0..3  (16-row wave tile)
    const int wnt = wave & 1;           // 0..1  (32-col wave tile)

    // staging: wave stages 4 of 32 frag-tiles: t = wave*4 + i
    const __hip_bfloat16* gsrc[4];
    int ldst[4];
    #pragma unroll
    for (int i = 0; i < 4; ++i) {
        const int t = wave * 4 + i;
        int row;
        const __hip_bfloat16* base;
        if (t < 16) { const int mt = t >> 2; row = m0 + mt * 16 + l15; base = A; }
        else        { const int u = t - 16;  row = n0 + (u >> 2) * 16 + l15; base = W; }
        gsrc[i] = base + (size_t)row * EN + (t & 3) * 32 + lq * 8;
        ldst[i] = t * 512;              // A at 0..8191, B at 8192..16383
    }

    f32x4 acc[2] = {};

    #pragma unroll
    for (int i = 0; i < 4; ++i) gll16(gsrc[i], &lds[ldst[i]]);
    __syncthreads();

    int p = 0;
    for (int k0 = 128; k0 <= EN; k0 += 128) {
        if (k0 < EN) {
            const int q = p ^ 1;
            #pragma unroll
            for (int i = 0; i < 4; ++i) gll16(gsrc[i] + k0, &lds[q * 16384 + ldst[i]]);
        }
        const __hip_bfloat16* Ab = &lds[p * 16384];
        const __hip_bfloat16* Bb = Ab + 8192;
        #pragma unroll
        for (int kt = 0; kt < 4; ++kt) {
            s16x8 a = *(const s16x8*)&Ab[(wmt * 4 + kt) * 512 + lane * 8];
            #pragma unroll
            for (int j = 0; j < 2; ++j) {
                s16x8 b = *(const s16x8*)&Bb[((wnt * 2 + j) * 4 + kt) * 512 + lane * 8];
                acc[j] = __builtin_amdgcn_mfma_f32_16x16x32_bf16(a, b, acc[j], 0, 0, 0);
            }
        }
        __syncthreads();
        p ^= 1;
    }

    if (EPI == 0) {
        // quantum epilogue: acc -> LDS f32 64x68 -> cos/products -> bf16 V
        float* sb = (float*)smem;                       // 17408 B, bufs dead
        #pragma unroll
        for (int j = 0; j < 2; ++j) {
            const int col = wnt * 32 + j * 16 + l15;
            #pragma unroll
            for (int r = 0; r < 4; ++r)
                sb[(wmt * 16 + lq * 4 + r) * 68 + col] = acc[j][r];
        }
        __syncthreads();
        const int row = tid >> 3, g = tid & 7;          // 64 rows x 8 groups
        const float* pv = &sb[row * 68 + g * 8];
        float t[8];
        #pragma unroll
        for (int j = 0; j < 8; ++j) t[j] = __cosf(pv[j] + rx[j]);
        Frag o;
        float suf = t[1];
        #pragma unroll
        for (int j = 2; j < 8; ++j) suf *= t[j];
        o.h[0] = __float2bfloat16(suf);
        float pr = t[0];
        #pragma unroll
        for (int j = 1; j < 8; ++j) { pr *= t[j]; o.h[j] = __float2bfloat16(pr); }
        __hip_bfloat16* V = (__hip_bfloat16*)Cv;
        *(s16x8*)(V + (size_t)(m0 + row) * EN + n0 + g * 8) = o.v;
    } else {
        float* C = (float*)Cv;
        #pragma unroll
        for (int j = 0; j < 2; ++j) {
            const int col = n0 + wnt * 32 + j * 16 + l15;
            const float bv = bias[col];
            #pragma unroll
            for (int r = 0; r < 4; ++r) {
                const int row = m0 + wmt * 16 + lq * 4 + r;
                C[(size_t)row * EN + col] = acc[j][r] + bv;
            }
        }
    }
}

extern "C" void kernel_launch(void* const* d_in, const int* in_sizes, int n_in,
                              void* d_out, int out_size, void* d_ws, size_t ws_size,
                              hipStream_t stream)
{
    // inputs: x, wq, wk, wv, wc, bc, rx_params (wq/wk dead: S==1)
    const float* x  = (const float*)d_in[0];
    const float* wv = (const float*)d_in[3];
    const float* wc = (const float*)d_in[4];
    const float* bc = (const float*)d_in[5];
    const float* rx = (const float*)d_in[6];
    float* out = (float*)d_out;

    const size_t XE = (size_t)BB * EN;   // 2M elems
    const size_t WE = (size_t)EN * EN;   // 1M elems

    // ws (12 MB): [xb 4MB | wvb 2MB | wcb 2MB | V 4MB]
    __hip_bfloat16* xb  = (__hip_bfloat16*)d_ws;
    __hip_bfloat16* wvb = xb + XE;
    __hip_bfloat16* wcb = wvb + WE;
    __hip_bfloat16* V   = wcb + WE;

    dim3 grid(BB / 64, EN / 64);         // 32 x 16 = 512 blocks
    cvt3_kernel<<<(int)((XE / 8 + 2 * (WE / 8)) / 256), 256, 0, stream>>>(
        x, wv, wc, xb, wvb, wcb);
    gemm_kernel<0><<<grid, 512, 0, stream>>>(xb, wvb, nullptr, rx, V);
    gemm_kernel<1><<<grid, 512, 0, stream>>>(V, wcb, bc, nullptr, out);
}